// Round 13
// baseline (24985.472 us; speedup 1.0000x reference)
//
#include <hip/hip_runtime.h>

#define RS 1024   // reservoir
#define SL 4096   // seq len
#define NB 1024   // batch
#define NI 16     // input size
#define RGRP 32   // batch rows per group
#define NGRP 32   // groups
#define WPG 8     // WGs per group (8 * 128 cols = 1024)

typedef short s8v __attribute__((ext_vector_type(8)));
typedef float f16v __attribute__((ext_vector_type(16)));
typedef unsigned int u4v __attribute__((ext_vector_type(4)));

#define WAIT_VM0 do { asm volatile("s_waitcnt vmcnt(0)" ::: "memory"); \
                      __builtin_amdgcn_sched_barrier(0); } while (0)

static __device__ __forceinline__ unsigned short f2bf(float f) {
  unsigned u = __float_as_uint(f);
  u += 0x7fffu + ((u >> 16) & 1u);          // round-to-nearest-even
  return (unsigned short)(u >> 16);
}
static __device__ __forceinline__ float bf2f(unsigned short b) {
  return __uint_as_float(((unsigned)b) << 16);
}
static __device__ __forceinline__ float fast_tanh(float a) {
  float e = __expf(2.0f * a);
  return 1.0f - 2.0f / (e + 1.0f);
}

// ---- L1+L2-bypassing ops (sc0 sc1): coherent at the LLC ----
static __device__ __forceinline__ u4v ld_llc_b128(const void* p) {
  u4v d;
  asm volatile("global_load_dwordx4 %0, %1, off sc0 sc1"
               : "=v"(d) : "v"(p) : "memory");
  return d;
}
static __device__ __forceinline__ void st_llc_b128(void* p, u4v d) {
  asm volatile("global_store_dwordx4 %0, %1, off sc0 sc1"
               : : "v"(p), "v"(d) : "memory");
}

// prep: W fp32 -> bf16; h0 = zeros (tag 0 = fresh for t=0, tau(0)=0);
// h1 = 0x00010000 dwords (tag 1 != tau(1)=0 -> stale-detectable).
__global__ __launch_bounds__(256) void prep_kernel(
    const float* __restrict__ W, unsigned short* __restrict__ wbf,
    uint4* __restrict__ h0q, uint4* __restrict__ h1q) {
  int idx = blockIdx.x * 256 + threadIdx.x;
  if (idx < RS * RS) wbf[idx] = f2bf(W[idx]);
  if (idx < (NB * RS) / 8) {
    h0q[idx] = make_uint4(0u, 0u, 0u, 0u);
    h1q[idx] = make_uint4(0x00010000u, 0x00010000u, 0x00010000u, 0x00010000u);
  }
}

// K-split W-register-resident recurrence; FLAG-FREE LLC h-exchange:
// the data carries a 1-bit step tag (bit16 of every dword = LSB of odd-k
// bf16), tag tau(s) = (s>>1)&1 alternates between consecutive writes of a
// double-buffer slot. Poll = load the A-frags themselves + tag check; on
// pass the operands are already in registers. No flags, no store drain.
// h layout (hx): h[c8][row][8] bf16. 256 WGs x 256 threads (4 waves).
// Group g = bid&31 owns rows [32g,+32); WG j = bid>>5 owns cols [128j,+128).
// Wave w: K-quarter [256w,+256) for all 128 WG cols; owns col-tile w.
__global__ __launch_bounds__(256, 1) void esn_kernel(
    const float* __restrict__ x, const float* __restrict__ Win,
    const unsigned short* __restrict__ wbf,
    unsigned short* __restrict__ hA, unsigned short* __restrict__ hB) {
  extern __shared__ char smem[];
  char* psm = smem;              // 64 KB: 16 partial slots [tile c][producer w]
  char* ctile = smem + 65536;    // 8 KB: 4 x (32x32 bf16) per-wave C tiles

  const int bid = blockIdx.x;
  const int g = bid & 31;        // group (mates share bid%8 -> same-XCD heuristic)
  const int j = bid >> 5;        // WG-in-group 0..7
  const int tid = threadIdx.x;
  const int w = tid >> 6;        // wave 0..3 = K-quarter, owns col-tile w
  const int lane = tid & 63;
  const int l31 = lane & 31;
  const int hi = lane >> 5;      // k-half 0..1

  const int n0 = j * 128 + w * 32;   // wave's OWN 32-col base (tile w)
  const int m0 = g * RGRP;           // group row base

  // ---- persistent W fragments: 4 tiles x 16 kk = 256 regs (AGPR file) ----
  s8v bw[4][16];
#pragma unroll
  for (int idx = 0; idx < 4; idx++) {
    const int c = (w + idx) & 3;
    const unsigned short* wp =
        wbf + (size_t)(j * 128 + c * 32 + l31) * RS + w * 256 + hi * 8;
#pragma unroll
    for (int kk = 0; kk < 16; kk++) bw[idx][kk] = *(const s8v*)(wp + kk * 16);
  }

  // ---- input-proj Win fragments hi/lo for OWN tile cols ----
  union U8 { s8v v; unsigned short u[8]; };
  U8 whi, wlo;
  {
    const float* p = Win + (n0 + l31) * NI + hi * 8;
#pragma unroll
    for (int i = 0; i < 8; i++) {
      float f = p[i];
      unsigned short h16 = f2bf(f);
      whi.u[i] = h16;
      wlo.u[i] = f2bf(f - bf2f(h16));
    }
  }

  const float* xrow = x + (size_t)(m0 + l31) * SL * NI + hi * 8;
  // A-frag global base: c8 = 32w + 2kk + hi, row = m0 + l31
  const size_t ab_off = (((size_t)(32 * w + hi) * NB) + m0 + l31) << 4;
  char* wct = ctile + w * 2048;                 // this wave's 32x32 C tile
  const unsigned oddm = (unsigned)(l31 & 1);    // lane holds odd-k cols iff set
  int dead = 0;

  // ---- prologue: issue t=0 A-frag loads + x(0) ----
  u4v al[16];
#pragma unroll
  for (int kk = 0; kk < 16; kk++)
    al[kk] = ld_llc_b128((const char*)hA + ab_off + (size_t)kk * (2 * NB * 16));
  float4 xa = *(const float4*)(xrow);
  float4 xb = *(const float4*)(xrow + 4);

  for (int t = 0; t < SL; t++) {
    const char* hsrc = (const char*)((t & 1) ? hB : hA);
    char* hdst = (char*)((t & 1) ? hA : hB);

    // ---- data-tag poll: loads already in flight; check bit16 of dwords ----
    if (!dead) {
      int spins = 0;
      const unsigned want = (unsigned)((t >> 1) & 1);
      for (;;) {
        WAIT_VM0;
        unsigned red;
        if (want) {
          red = 0xFFFFFFFFu;
#pragma unroll
          for (int kk = 0; kk < 16; kk++)
            red &= al[kk].x & al[kk].y & al[kk].z & al[kk].w;
          red = (red >> 16) & 1u;            // 1 iff every dword tagged 1
        } else {
          red = 0u;
#pragma unroll
          for (int kk = 0; kk < 16; kk++)
            red |= al[kk].x | al[kk].y | al[kk].z | al[kk].w;
          red = ((red >> 16) & 1u) ^ 1u;     // 1 iff every dword tagged 0
        }
        if (__all((int)red)) break;
        if (++spins > (1 << 12)) { dead = 1; break; }   // sticky: degrade, no hang
        __builtin_amdgcn_s_sleep(1);
#pragma unroll
        for (int kk = 0; kk < 16; kk++)
          al[kk] = ld_llc_b128(hsrc + ab_off + (size_t)kk * (2 * NB * 16));
      }
    } else {
      WAIT_VM0;   // keep vmcnt ledger sane in degraded mode
    }

    // ---- x fragments hi/lo (A: row=l31, k=8hi+i) ----
    U8 xhi, xlo;
    {
      float xf[8] = {xa.x, xa.y, xa.z, xa.w, xb.x, xb.y, xb.z, xb.w};
#pragma unroll
      for (int i = 0; i < 8; i++) {
        unsigned short h16 = f2bf(xf[i]);
        xhi.u[i] = h16;
        xlo.u[i] = f2bf(xf[i] - bf2f(h16));
      }
    }

    // ---- input projection into OWN-tile acc ----
    f16v acc[4];
    {
      f16v z = {};
      z = __builtin_amdgcn_mfma_f32_32x32x16_bf16(xhi.v, whi.v, z, 0, 0, 0);
      z = __builtin_amdgcn_mfma_f32_32x32x16_bf16(xlo.v, whi.v, z, 0, 0, 0);
      acc[0] = __builtin_amdgcn_mfma_f32_32x32x16_bf16(xhi.v, wlo.v, z, 0, 0, 0);
      f16v zz = {};
      acc[1] = zz; acc[2] = zz; acc[3] = zz;
    }

    // ---- K-quarter MFMAs: operands fully resident, no waits ----
#pragma unroll
    for (int kk = 0; kk < 16; kk++) {
      union AU { u4v u; s8v s; } au; au.u = al[kk];
#pragma unroll
      for (int idx = 0; idx < 4; idx++)
        acc[idx] = __builtin_amdgcn_mfma_f32_32x32x16_bf16(au.s, bw[idx][kk], acc[idx], 0, 0, 0);
    }

    // ---- write partials for non-owned tiles to LDS (slot = tile*4 + w) ----
#pragma unroll
    for (int idx = 1; idx < 4; idx++) {
      const int c = (w + idx) & 3;
      char* slot = psm + (((c << 2) | w) << 12) + (size_t)l31 * 4;
#pragma unroll
      for (int r = 0; r < 16; r++)
        *(float*)(slot + (hi * 16 + r) * 128) = acc[idx][r];
    }
    __syncthreads();   // bar1: partials visible

    // ---- reduce own tile: acc[0] + 3 partials from LDS ----
    f16v own = acc[0];
#pragma unroll
    for (int idx = 1; idx < 4; idx++) {
      const int wp = (w + idx) & 3;
      const char* slot = psm + (((w << 2) | wp) << 12) + (size_t)l31 * 4;
#pragma unroll
      for (int r = 0; r < 16; r++)
        own[r] += *(const float*)(slot + (hi * 16 + r) * 128);
    }

    // ---- tanh -> bf16 with step tag -> per-wave LDS C-tile ----
    const unsigned taun = (unsigned)(((t + 1) >> 1) & 1);
#pragma unroll
    for (int r = 0; r < 16; r++) {
      const int row = (r & 3) + 8 * (r >> 2) + 4 * hi;
      unsigned short hv = f2bf(fast_tanh(own[r]));
      hv = (unsigned short)(((unsigned)hv & ~oddm) | (taun & oddm));
      *(unsigned short*)(wct + row * 64 + l31 * 2) = hv;
    }
    asm volatile("s_waitcnt lgkmcnt(0)" ::: "memory");   // wave-local transpose
    __builtin_amdgcn_sched_barrier(0);
    // ---- transpose-read C tile -> hx-layout LLC stores (no drain, no flag) ----
    {
      const int row = lane >> 1, c = lane & 1;
      u4v v0 = *(const u4v*)(wct + row * 64 + c * 16);
      u4v v1 = *(const u4v*)(wct + row * 64 + c * 16 + 32);
      char* g0 = hdst + ((((size_t)(n0 >> 3) + c) * NB + m0 + row) << 4);
      char* g1 = hdst + ((((size_t)(n0 >> 3) + c + 2) * NB + m0 + row) << 4);
      st_llc_b128(g0, v0);
      st_llc_b128(g1, v1);
    }

    // ---- speculative prefetch of next step's A-frags + x (tag-gated later) ----
#pragma unroll
    for (int kk = 0; kk < 16; kk++)
      al[kk] = ld_llc_b128(hdst + ab_off + (size_t)kk * (2 * NB * 16));
    {
      const size_t xo = (size_t)((t + 1 < SL) ? t + 1 : 0) * NI;
      xa = *(const float4*)(xrow + xo);
      xb = *(const float4*)(xrow + xo + 4);
    }
    __syncthreads();   // bar2: protect partial slots and wct for next step
  }
}

// y = h_final @ Wout^T + b ; h in hx layout: elem (b,k) at hx[k>>3][b][k&7]
__global__ __launch_bounds__(256) void yout_kernel(
    const unsigned short* __restrict__ h, const float* __restrict__ Wout,
    const float* __restrict__ bias, float* __restrict__ y) {
  const int tid = threadIdx.x;
  const int b = (blockIdx.x << 4) + (tid >> 4);
  const int o = tid & 15;
  const float* wr = Wout + (o << 10);
  float s = 0.0f;
  for (int k8 = 0; k8 < RS / 8; k8++) {
    const unsigned short* hc = h + (((size_t)k8 * NB + b) << 3);
#pragma unroll
    for (int i = 0; i < 8; i++) s += bf2f(hc[i]) * wr[k8 * 8 + i];
  }
  y[(b << 4) + o] = s + bias[o];
}

extern "C" void kernel_launch(void* const* d_in, const int* in_sizes, int n_in,
                              void* d_out, int out_size, void* d_ws, size_t ws_size,
                              hipStream_t stream) {
  const float* x = (const float*)d_in[0];
  const float* Win = (const float*)d_in[1];
  const float* W = (const float*)d_in[2];
  const float* Wout = (const float*)d_in[3];
  const float* bias = (const float*)d_in[4];
  float* y = (float*)d_out;

  char* ws = (char*)d_ws;
  unsigned short* hA = (unsigned short*)ws;                  // 2 MB (final h)
  unsigned short* hB = (unsigned short*)(ws + (1 << 21));    // 2 MB
  unsigned short* wbf = (unsigned short*)(ws + (2 << 21));   // 2 MB (W bf16)

  (void)hipFuncSetAttribute((const void*)esn_kernel,
                            hipFuncAttributeMaxDynamicSharedMemorySize, 73728);

  prep_kernel<<<4096, 256, 0, stream>>>(W, wbf, (uint4*)hA, (uint4*)hB);
  esn_kernel<<<NGRP * WPG, 256, 73728, stream>>>(x, Win, wbf, hA, hB);
  yout_kernel<<<64, 256, 0, stream>>>(hA, Wout, bias, y);
}

// Round 15
// 17564.876 us; speedup vs baseline: 1.4225x; 1.4225x over previous
//
#include <hip/hip_runtime.h>

#define RS 1024   // reservoir
#define SL 4096   // seq len
#define NB 1024   // batch
#define NI 16     // input size
#define RGRP 32   // batch rows per group
#define NGRP 32   // groups
#define WPG 8     // WGs per group (8 * 128 cols = 1024)

typedef short s8v __attribute__((ext_vector_type(8)));
typedef float f16v __attribute__((ext_vector_type(16)));
typedef unsigned int u4v __attribute__((ext_vector_type(4)));

#define WAIT_VM0 do { asm volatile("s_waitcnt vmcnt(0)" ::: "memory"); \
                      __builtin_amdgcn_sched_barrier(0); } while (0)

static __device__ __forceinline__ unsigned short f2bf(float f) {
  unsigned u = __float_as_uint(f);
  u += 0x7fffu + ((u >> 16) & 1u);          // round-to-nearest-even
  return (unsigned short)(u >> 16);
}
static __device__ __forceinline__ float bf2f(unsigned short b) {
  return __uint_as_float(((unsigned)b) << 16);
}
static __device__ __forceinline__ float fast_tanh(float a) {
  float e = __expf(2.0f * a);
  return 1.0f - 2.0f / (e + 1.0f);
}

// ---- L1+L2-bypassing ops (sc0 sc1): coherent at the LLC ----
static __device__ __forceinline__ u4v ld_llc_b128(const void* p) {
  u4v d;
  asm volatile("global_load_dwordx4 %0, %1, off sc0 sc1"
               : "=v"(d) : "v"(p) : "memory");
  return d;
}
static __device__ __forceinline__ void st_llc_b128(void* p, u4v d) {
  asm volatile("global_store_dwordx4 %0, %1, off sc0 sc1"
               : : "v"(p), "v"(d) : "memory");
}

// prep: W fp32 -> bf16; h0 = zeros (tag bits (0,0) = tau2(0)=0, fresh for
// t=0); h1 = 0x00010001 dwords (tag (1,1)=3 != tau2(1)=0 -> stale-detectable).
__global__ __launch_bounds__(256) void prep_kernel(
    const float* __restrict__ W, unsigned short* __restrict__ wbf,
    uint4* __restrict__ h0q, uint4* __restrict__ h1q) {
  int idx = blockIdx.x * 256 + threadIdx.x;
  if (idx < RS * RS) wbf[idx] = f2bf(W[idx]);
  if (idx < (NB * RS) / 8) {
    h0q[idx] = make_uint4(0u, 0u, 0u, 0u);
    h1q[idx] = make_uint4(0x00010001u, 0x00010001u, 0x00010001u, 0x00010001u);
  }
}

// K-split W-register-resident recurrence; FLAG-FREE LLC h-exchange with a
// 2-bit generation tag embedded in the data (LSB of every bf16; dword bits
// 0 and 16). tau2(s) = (s>>1)&3 distinguishes 4 generations of a buffer
// slot. Poll = the A-frag loads themselves, issued ~1.1k cy after the local
// stores (calibrated so producers' stores land first); on pass the operands
// are already in registers. No flags, no store drains, no atomics.
// h layout (hx): h[c8][row][8] bf16. 256 WGs x 256 threads (4 waves).
// Group g = bid&31 owns rows [32g,+32); WG j = bid>>5 owns cols [128j,+128).
// Wave w: K-quarter [256w,+256) for all 128 WG cols; owns col-tile w.
__global__ __launch_bounds__(256, 1) void esn_kernel(
    const float* __restrict__ x, const float* __restrict__ Win,
    const unsigned short* __restrict__ wbf,
    unsigned short* __restrict__ hA, unsigned short* __restrict__ hB) {
  extern __shared__ char smem[];
  char* psm = smem;              // 64 KB: 16 partial slots [tile c][producer w]
  char* ctile = smem + 65536;    // 8 KB: 4 x (32x32 bf16) per-wave C tiles

  const int bid = blockIdx.x;
  const int g = bid & 31;        // group
  const int j = bid >> 5;        // WG-in-group 0..7
  const int tid = threadIdx.x;
  const int w = tid >> 6;        // wave 0..3 = K-quarter, owns col-tile w
  const int lane = tid & 63;
  const int l31 = lane & 31;
  const int hi = lane >> 5;      // k-half 0..1

  const int n0 = j * 128 + w * 32;   // wave's OWN 32-col base (tile w)
  const int m0 = g * RGRP;           // group row base

  // ---- persistent W fragments: 4 tiles x 16 kk = 256 regs ----
  s8v bw[4][16];
#pragma unroll
  for (int idx = 0; idx < 4; idx++) {
    const int c = (w + idx) & 3;
    const unsigned short* wp =
        wbf + (size_t)(j * 128 + c * 32 + l31) * RS + w * 256 + hi * 8;
#pragma unroll
    for (int kk = 0; kk < 16; kk++) bw[idx][kk] = *(const s8v*)(wp + kk * 16);
  }

  // ---- input-proj Win fragments hi/lo for OWN tile cols ----
  union U8 { s8v v; unsigned short u[8]; };
  U8 whi, wlo;
  {
    const float* p = Win + (n0 + l31) * NI + hi * 8;
#pragma unroll
    for (int i = 0; i < 8; i++) {
      float f = p[i];
      unsigned short h16 = f2bf(f);
      whi.u[i] = h16;
      wlo.u[i] = f2bf(f - bf2f(h16));
    }
  }

  const float* xrow = x + (size_t)(m0 + l31) * SL * NI + hi * 8;
  // A-frag global base: c8 = 32w + 2kk + hi, row = m0 + l31
  const size_t ab_off = (((size_t)(32 * w + hi) * NB) + m0 + l31) << 4;
  char* wct = ctile + w * 2048;                 // this wave's 32x32 C tile
  int dead = 0;

  // prologue: x(0) (compiler inserts waits before first use)
  float4 xa = *(const float4*)(xrow);
  float4 xb = *(const float4*)(xrow + 4);

  for (int t = 0; t < SL; t++) {
    const char* hsrc = (const char*)((t & 1) ? hB : hA);
    char* hdst = (char*)((t & 1) ? hA : hB);

    // ---- issue the 16 A-frag loads (the poll IS the data) ----
    u4v al[16];
#pragma unroll
    for (int kk = 0; kk < 16; kk++)
      al[kk] = ld_llc_b128(hsrc + ab_off + (size_t)kk * (2 * NB * 16));

    // ---- x fragments hi/lo + input projection (fills the load flight) ----
    U8 xhi, xlo;
    {
      float xf[8] = {xa.x, xa.y, xa.z, xa.w, xb.x, xb.y, xb.z, xb.w};
#pragma unroll
      for (int i = 0; i < 8; i++) {
        unsigned short h16 = f2bf(xf[i]);
        xhi.u[i] = h16;
        xlo.u[i] = f2bf(xf[i] - bf2f(h16));
      }
    }
    f16v acc[4];
    {
      f16v z = {};
      z = __builtin_amdgcn_mfma_f32_32x32x16_bf16(xhi.v, whi.v, z, 0, 0, 0);
      z = __builtin_amdgcn_mfma_f32_32x32x16_bf16(xlo.v, whi.v, z, 0, 0, 0);
      acc[0] = __builtin_amdgcn_mfma_f32_32x32x16_bf16(xhi.v, wlo.v, z, 0, 0, 0);
      f16v zz = {};
      acc[1] = zz; acc[2] = zz; acc[3] = zz;
    }

    // ---- tag check: pattern = (tau2&1) | ((tau2>>1)<<16) on every dword ----
    {
      const unsigned tau2 = (unsigned)((t >> 1) & 3);
      const unsigned pat = (tau2 & 1u) | ((tau2 >> 1) << 16);
      int spins = 0;
      while (!dead) {
        WAIT_VM0;
        unsigned orv = 0u;
#pragma unroll
        for (int kk = 0; kk < 16; kk++) {
          orv |= (al[kk].x ^ pat);
          orv |= (al[kk].y ^ pat);
          orv |= (al[kk].z ^ pat);
          orv |= (al[kk].w ^ pat);
        }
        if (__all((int)((orv & 0x00010001u) == 0u))) break;
        __builtin_amdgcn_s_sleep(2);
        if (++spins > (1 << 12)) { dead = 1; break; }   // sticky: degrade, no hang
#pragma unroll
        for (int kk = 0; kk < 16; kk++)
          al[kk] = ld_llc_b128(hsrc + ab_off + (size_t)kk * (2 * NB * 16));
      }
      if (dead) WAIT_VM0;   // keep ledger sane in degraded mode
    }

    // ---- K-quarter MFMAs: operands fully resident, no waits ----
#pragma unroll
    for (int kk = 0; kk < 16; kk++) {
      union AU { u4v u; s8v s; } au; au.u = al[kk];
#pragma unroll
      for (int idx = 0; idx < 4; idx++)
        acc[idx] = __builtin_amdgcn_mfma_f32_32x32x16_bf16(au.s, bw[idx][kk], acc[idx], 0, 0, 0);
    }

    // ---- write partials for non-owned tiles to LDS (slot = tile*4 + w) ----
#pragma unroll
    for (int idx = 1; idx < 4; idx++) {
      const int c = (w + idx) & 3;
      char* slot = psm + (((c << 2) | w) << 12) + (size_t)l31 * 4;
#pragma unroll
      for (int r = 0; r < 16; r++)
        *(float*)(slot + (hi * 16 + r) * 128) = acc[idx][r];
    }
    __syncthreads();   // bar1: partials visible (nothing outstanding -> cheap)

    // ---- reduce own tile: acc[0] + 3 partials from LDS ----
    f16v own = acc[0];
#pragma unroll
    for (int idx = 1; idx < 4; idx++) {
      const int wp = (w + idx) & 3;
      const char* slot = psm + (((w << 2) | wp) << 12) + (size_t)l31 * 4;
#pragma unroll
      for (int r = 0; r < 16; r++)
        own[r] += *(const float*)(slot + (hi * 16 + r) * 128);
    }

    // ---- tanh -> bf16 with generation tag in LSB -> per-wave LDS C-tile ----
    {
      const unsigned tau2n = (unsigned)(((t + 1) >> 1) & 3);
      const unsigned mybit = (l31 & 1) ? ((tau2n >> 1) & 1u) : (tau2n & 1u);
#pragma unroll
      for (int r = 0; r < 16; r++) {
        const int row = (r & 3) + 8 * (r >> 2) + 4 * hi;
        unsigned short hv = f2bf(fast_tanh(own[r]));
        hv = (unsigned short)(((unsigned)hv & ~1u) | mybit);
        *(unsigned short*)(wct + row * 64 + l31 * 2) = hv;
      }
    }
    asm volatile("s_waitcnt lgkmcnt(0)" ::: "memory");   // wave-local transpose
    __builtin_amdgcn_sched_barrier(0);
    // ---- transpose-read C tile -> hx-layout stores (NO drain, NO flag) ----
    {
      const int row = lane >> 1, c = lane & 1;
      u4v v0 = *(const u4v*)(wct + row * 64 + c * 16);
      u4v v1 = *(const u4v*)(wct + row * 64 + c * 16 + 32);
      char* g0 = hdst + ((((size_t)(n0 >> 3) + c) * NB + m0 + row) << 4);
      char* g1 = hdst + ((((size_t)(n0 >> 3) + c + 2) * NB + m0 + row) << 4);
      st_llc_b128(g0, v0);
      st_llc_b128(g1, v1);
    }

    // ---- calibrated spacing: x(t+1) prefetch + sleep, then barrier ----
    {
      const size_t xo = (size_t)((t + 1 < SL) ? t + 1 : 0) * NI;
      xa = *(const float4*)(xrow + xo);
      xb = *(const float4*)(xrow + xo + 4);
    }
    __builtin_amdgcn_s_sleep(16);   // ~1024 cy: lets producer stores land
    __syncthreads();                // bar2: protects slots; drains during sleep
  }
}

// y = h_final @ Wout^T + b ; h in hx layout: elem (b,k) at hx[k>>3][b][k&7]
__global__ __launch_bounds__(256) void yout_kernel(
    const unsigned short* __restrict__ h, const float* __restrict__ Wout,
    const float* __restrict__ bias, float* __restrict__ y) {
  const int tid = threadIdx.x;
  const int b = (blockIdx.x << 4) + (tid >> 4);
  const int o = tid & 15;
  const float* wr = Wout + (o << 10);
  float s = 0.0f;
  for (int k8 = 0; k8 < RS / 8; k8++) {
    const unsigned short* hc = h + (((size_t)k8 * NB + b) << 3);
#pragma unroll
    for (int i = 0; i < 8; i++) s += bf2f(hc[i]) * wr[k8 * 8 + i];
  }
  y[(b << 4) + o] = s + bias[o];
}

extern "C" void kernel_launch(void* const* d_in, const int* in_sizes, int n_in,
                              void* d_out, int out_size, void* d_ws, size_t ws_size,
                              hipStream_t stream) {
  const float* x = (const float*)d_in[0];
  const float* Win = (const float*)d_in[1];
  const float* W = (const float*)d_in[2];
  const float* Wout = (const float*)d_in[3];
  const float* bias = (const float*)d_in[4];
  float* y = (float*)d_out;

  char* ws = (char*)d_ws;
  unsigned short* hA = (unsigned short*)ws;                  // 2 MB (final h)
  unsigned short* hB = (unsigned short*)(ws + (1 << 21));    // 2 MB
  unsigned short* wbf = (unsigned short*)(ws + (2 << 21));   // 2 MB (W bf16)

  (void)hipFuncSetAttribute((const void*)esn_kernel,
                            hipFuncAttributeMaxDynamicSharedMemorySize, 73728);

  prep_kernel<<<4096, 256, 0, stream>>>(W, wbf, (uint4*)hA, (uint4*)hB);
  esn_kernel<<<NGRP * WPG, 256, 73728, stream>>>(x, Win, wbf, hA, hB);
  yout_kernel<<<64, 256, 0, stream>>>(hA, Wout, bias, y);
}